// Round 1
// baseline (204.079 us; speedup 1.0000x reference)
//
#include <hip/hip_runtime.h>
#include <hip/hip_bf16.h>
#include <math.h>

#define BATCH 8
#define NPTS 4096
#define CH 128
#define TILE 128

typedef __attribute__((ext_vector_type(4))) float f32x4;
typedef __attribute__((ext_vector_type(8))) short bf16x8;

typedef __attribute__((address_space(3))) unsigned int lds_uint;
typedef __attribute__((address_space(1))) const unsigned int gbl_uint;

__device__ __forceinline__ void load_lds16(const void* g, const void* l) {
    __builtin_amdgcn_global_load_lds((gbl_uint*)g, (lds_uint*)l, 16, 0, 0);
}

// ---------------------------------------------------------------------------
// Kernel 1: L2-normalize each point (column of features[b][:, n]) into bf16
// vn[b][n][c] (C contiguous), and zero the pos/neg accumulators.
// ---------------------------------------------------------------------------
__global__ __launch_bounds__(256) void normalize_kernel(
    const float* __restrict__ f, __hip_bfloat16* __restrict__ vn,
    float* __restrict__ pos, float* __restrict__ neg)
{
    int idx = blockIdx.x * 256 + threadIdx.x;      // 0 .. 32767 == b*4096 + n
    int b = idx >> 12;
    int n = idx & (NPTS - 1);
    const float* base = f + (size_t)b * CH * NPTS + n;

    float ss = 0.0f;
    #pragma unroll 8
    for (int c = 0; c < CH; c++) {
        float x = base[(size_t)c * NPTS];
        ss += x * x;
    }
    float nrm = sqrtf(ss);
    float scale = 1.0f / fmaxf(nrm, 1e-12f);

    __hip_bfloat16* out = vn + (size_t)idx * CH;
    #pragma unroll
    for (int c0 = 0; c0 < CH; c0 += 8) {
        union { __hip_bfloat16 h[8]; uint4 u; } pk;
        #pragma unroll
        for (int j = 0; j < 8; j++)
            pk.h[j] = __float2bfloat16(base[(size_t)(c0 + j) * NPTS] * scale);
        *((uint4*)(out + c0)) = pk.u;
    }
    pos[idx] = 0.0f;
    neg[idx] = 0.0f;
}

// ---------------------------------------------------------------------------
// Kernel 2: fused 128x128-tile bf16 MFMA GEMM (K=128, single pass) +
// exp/diag/label-mask epilogue accumulating per-row pos/neg.
// Grid: (col_tiles=32, row_tiles=32, batch=8), block = 256 threads (4 waves).
// Wave w owns tile rows [w*32, w*32+32), all 128 cols.
// ---------------------------------------------------------------------------
__global__ __launch_bounds__(256, 2) void tile_kernel(
    const __hip_bfloat16* __restrict__ vn, const int* __restrict__ labels,
    float* __restrict__ pos, float* __restrict__ neg)
{
    // LDS tiles, row-major [row][k] in 8-element (16 B) chunks; chunk index is
    // XOR-swizzled by (row & 15) at *global fetch* time so that fragment
    // ds_read_b128 (16 lanes, consecutive rows, same k-chunk) spreads across
    // bank clusters instead of a 16-way same-bank pileup.
    __shared__ short lA[TILE * CH];   // 32 KB
    __shared__ short lB[TILE * CH];   // 32 KB
    __shared__ int labR[TILE], labC[TILE];

    const int b    = blockIdx.z;
    const int rt   = blockIdx.y, ct = blockIdx.x;
    const int tid  = threadIdx.x;
    const int wave = tid >> 6, lane = tid & 63;
    const int lane15 = lane & 15, quad = lane >> 4;

    const int row0 = rt * TILE, col0 = ct * TILE;
    const __hip_bfloat16* Ab = vn + ((size_t)b * NPTS + row0) * CH;
    const __hip_bfloat16* Bb = vn + ((size_t)b * NPTS + col0) * CH;

    // Stage labels for this tile's rows and cols.
    if (tid < 128)        labR[tid]        = labels[b * NPTS + row0 + tid];
    else                  labC[tid - 128]  = labels[b * NPTS + col0 + (tid - 128)];

    // Async global -> LDS staging. Per wave, iter i covers 4 rows x 16 chunks.
    // LDS dest is wave-uniform base + lane*16B (HW rule); lane l lands at
    // row (l>>4), chunk (l&15). We source global chunk (l&15) ^ (row & 15).
    {
        int rsw = (wave * 4 + quad) & 15;       // row & 15 (i*16 doesn't change it)
        int g   = lane15 ^ rsw;                 // swizzled global chunk
        #pragma unroll
        for (int i = 0; i < 8; i++) {
            int rowA = i * 16 + wave * 4 + quad;
            int ldsrow = i * 16 + wave * 4;     // wave-uniform
            load_lds16(Ab + (size_t)rowA * CH + g * 8, &lA[ldsrow * CH]);
            load_lds16(Bb + (size_t)rowA * CH + g * 8, &lB[ldsrow * CH]);
        }
    }
    __syncthreads();   // drains vmcnt (incl. global_load_lds) before use

    // MFMA main: acc[mi][ni], mi in {0,1} (16-row halves), ni in 0..7 (cols).
    f32x4 acc[2][8] = {};
    #pragma unroll
    for (int ks = 0; ks < 4; ks++) {
        int kg = ks * 4 + quad;                 // global k-chunk 0..15
        int chunk = (kg ^ lane15) << 3;         // swizzled LDS chunk offset (shorts)
        bf16x8 afrag[2], bfrag[8];
        #pragma unroll
        for (int mi = 0; mi < 2; mi++) {
            int m = wave * 32 + mi * 16 + lane15;    // m & 15 == lane15
            afrag[mi] = *(const bf16x8*)&lA[m * CH + chunk];
        }
        #pragma unroll
        for (int ni = 0; ni < 8; ni++) {
            int n = ni * 16 + lane15;                // n & 15 == lane15
            bfrag[ni] = *(const bf16x8*)&lB[n * CH + chunk];
        }
        #pragma unroll
        for (int mi = 0; mi < 2; mi++)
            #pragma unroll
            for (int ni = 0; ni < 8; ni++)
                acc[mi][ni] = __builtin_amdgcn_mfma_f32_16x16x32_bf16(
                    afrag[mi], bfrag[ni], acc[mi][ni], 0, 0, 0);
    }

    // Epilogue. C/D layout (verified m89/m91): col = lane&15, row = quad*4+reg.
    int labc[8];
    #pragma unroll
    for (int ni = 0; ni < 8; ni++) labc[ni] = labC[ni * 16 + lane15];

    #pragma unroll
    for (int mi = 0; mi < 2; mi++) {
        #pragma unroll
        for (int r = 0; r < 4; r++) {
            int row_l = wave * 32 + mi * 16 + quad * 4 + r;
            int grow  = row0 + row_l;
            int lr    = labR[row_l];
            float p = 0.0f, q = 0.0f;
            #pragma unroll
            for (int ni = 0; ni < 8; ni++) {
                float e = __expf(acc[mi][ni][r] * 10.0f);   // s / TEMP
                int gcol = col0 + ni * 16 + lane15;
                if (grow == gcol) e = 0.0f;                 // remove diagonal
                if (labc[ni] == lr) p += e; else q += e;
            }
            // Butterfly-reduce across the 16 lanes holding this row's cols.
            #pragma unroll
            for (int off = 1; off < 16; off <<= 1) {
                p += __shfl_xor(p, off);
                q += __shfl_xor(q, off);
            }
            if (lane15 == 0) {
                atomicAdd(&pos[b * NPTS + grow], p);
                atomicAdd(&neg[b * NPTS + grow], q);
            }
        }
    }
}

// ---------------------------------------------------------------------------
// Kernel 3: deviation_i = log((p+n)/p); mean over all 32768 rows == mean of
// per-cloud means (equal N). Single block, 1024 threads.
// ---------------------------------------------------------------------------
__global__ __launch_bounds__(1024) void finalize_kernel(
    const float* __restrict__ pos, const float* __restrict__ neg,
    float* __restrict__ out)
{
    float acc = 0.0f;
    for (int i = threadIdx.x; i < BATCH * NPTS; i += 1024) {
        float p = pos[i];
        float t = p + neg[i];
        acc += logf(t / p);     // == -log(p / (p+n))
    }
    #pragma unroll
    for (int off = 32; off; off >>= 1) acc += __shfl_down(acc, off);
    __shared__ float red[16];
    if ((threadIdx.x & 63) == 0) red[threadIdx.x >> 6] = acc;
    __syncthreads();
    if (threadIdx.x < 16) {
        float v = red[threadIdx.x];
        #pragma unroll
        for (int off = 8; off; off >>= 1) v += __shfl_down(v, off);
        if (threadIdx.x == 0) out[0] = v * (1.0f / (BATCH * NPTS));
    }
}

extern "C" void kernel_launch(void* const* d_in, const int* in_sizes, int n_in,
                              void* d_out, int out_size, void* d_ws, size_t ws_size,
                              hipStream_t stream)
{
    const float* features = (const float*)d_in[0];
    const int*   labels   = (const int*)d_in[1];
    float*       out      = (float*)d_out;

    // Workspace layout: vn bf16 [8][4096][128] = 8 MB, then pos/neg fp32.
    __hip_bfloat16* vn = (__hip_bfloat16*)d_ws;
    float* pos = (float*)((char*)d_ws + (size_t)BATCH * NPTS * CH * sizeof(__hip_bfloat16));
    float* neg = pos + BATCH * NPTS;

    hipLaunchKernelGGL(normalize_kernel, dim3(BATCH * NPTS / 256), dim3(256), 0, stream,
                       features, vn, pos, neg);
    hipLaunchKernelGGL(tile_kernel, dim3(NPTS / TILE, NPTS / TILE, BATCH), dim3(256), 0, stream,
                       vn, labels, pos, neg);
    hipLaunchKernelGGL(finalize_kernel, dim3(1), dim3(1024), 0, stream, pos, neg, out);
}

// Round 2
// 153.857 us; speedup vs baseline: 1.3264x; 1.3264x over previous
//
#include <hip/hip_runtime.h>
#include <hip/hip_bf16.h>
#include <math.h>

#define BATCH 8
#define NPTS 4096
#define CH 128
#define TILE 128

typedef __attribute__((ext_vector_type(4))) float f32x4;
typedef __attribute__((ext_vector_type(8))) short bf16x8;

typedef __attribute__((address_space(3))) unsigned int lds_uint;
typedef __attribute__((address_space(1))) const unsigned int gbl_uint;

__device__ __forceinline__ void load_lds16(const void* g, const void* l) {
    __builtin_amdgcn_global_load_lds((gbl_uint*)g, (lds_uint*)l, 16, 0, 0);
}

// ---------------------------------------------------------------------------
// Kernel 1: L2-normalize each point (column of features[b][:, n]) into bf16
// vn[b][n][c] (C contiguous), and zero the pos/neg accumulators.
// ---------------------------------------------------------------------------
__global__ __launch_bounds__(256) void normalize_kernel(
    const float* __restrict__ f, __hip_bfloat16* __restrict__ vn,
    float* __restrict__ pos, float* __restrict__ neg)
{
    int idx = blockIdx.x * 256 + threadIdx.x;      // 0 .. 32767 == b*4096 + n
    int b = idx >> 12;
    int n = idx & (NPTS - 1);
    const float* base = f + (size_t)b * CH * NPTS + n;

    float ss = 0.0f;
    #pragma unroll 8
    for (int c = 0; c < CH; c++) {
        float x = base[(size_t)c * NPTS];
        ss += x * x;
    }
    float nrm = sqrtf(ss);
    float scale = 1.0f / fmaxf(nrm, 1e-12f);

    __hip_bfloat16* out = vn + (size_t)idx * CH;
    #pragma unroll
    for (int c0 = 0; c0 < CH; c0 += 8) {
        union { __hip_bfloat16 h[8]; uint4 u; } pk;
        #pragma unroll
        for (int j = 0; j < 8; j++)
            pk.h[j] = __float2bfloat16(base[(size_t)(c0 + j) * NPTS] * scale);
        *((uint4*)(out + c0)) = pk.u;
    }
    pos[idx] = 0.0f;
    neg[idx] = 0.0f;
}

// ---------------------------------------------------------------------------
// Kernel 2 (symmetric): S = V V^T is symmetric, so only tiles rt <= ct are
// computed (528 of 1024 per batch). Off-diagonal tiles contribute BOTH a
// row-side reduction (sum over cols -> rows of rt-range) and a col-side
// reduction (sum over rows -> rows of ct-range); the label-match condition
// is identical for both. Diagonal tiles contribute row-side only, with the
// diagonal element zeroed.
//
// Block = 512 threads (8 waves), 128x128 tile, K=C=128 single shot.
// Wave w owns tile rows [w*16, w*16+16), all 128 cols.
// LDS ~74 KB -> 2 blocks/CU -> 16 waves/CU (4/SIMD).
// ---------------------------------------------------------------------------
__global__ __launch_bounds__(512, 4) void tile_kernel(
    const __hip_bfloat16* __restrict__ vn, const int* __restrict__ labels,
    float* __restrict__ pos, float* __restrict__ neg)
{
    // LDS tiles, row-major [row][k] in 8-elem (16 B) chunks; chunk index is
    // XOR-swizzled by (row & 15) at *global fetch* time (LDS write order of
    // global_load_lds is HW-fixed: wave-uniform base + lane*16B), so that
    // fragment ds_read_b128 spreads across bank clusters. R1 measured
    // SQ_LDS_BANK_CONFLICT = 0 with this scheme.
    __shared__ short lA[TILE * CH];        // 32 KB
    __shared__ short lB[TILE * CH];        // 32 KB
    __shared__ int labR[TILE], labC[TILE]; // 1 KB
    __shared__ float colT[8][TILE];        // 4 KB  per-wave col-sum partials
    __shared__ float colP[8][TILE];        // 4 KB

    const int b = blockIdx.z;

    // Decode linear pair index -> (rt, ct) with rt <= ct. <=32 scalar iters.
    int t = blockIdx.x, rt = 0;
    while (t >= 32 - rt) { t -= 32 - rt; rt++; }
    const int ct = rt + t;
    const bool diag = (rt == ct);

    const int tid = threadIdx.x;
    const int w = tid >> 6, lane = tid & 63;
    const int lane15 = lane & 15, quad = lane >> 4;

    const int row0 = rt * TILE, col0 = ct * TILE;
    const __hip_bfloat16* Ab = vn + ((size_t)b * NPTS + row0) * CH;
    const __hip_bfloat16* Bb = vn + ((size_t)b * NPTS + col0) * CH;

    if (tid < 128)       labR[tid]       = labels[b * NPTS + row0 + tid];
    else if (tid < 256)  labC[tid - 128] = labels[b * NPTS + col0 + (tid - 128)];

    // Async global -> LDS staging: per wave-iter, lanes cover 4 rows x 16
    // chunks. LDS lane dest = row (base+quad), chunk lane15; global source
    // chunk = lane15 ^ (row & 15).
    #pragma unroll
    for (int i = 0; i < 4; i++) {
        int rsw = (i * 4 + quad) & 15;
        int g   = lane15 ^ rsw;
        int row = w * 16 + i * 4 + quad;
        int ldsrow = w * 16 + i * 4;          // wave-uniform
        load_lds16(Ab + (size_t)row * CH + g * 8, &lA[ldsrow * CH]);
        load_lds16(Bb + (size_t)row * CH + g * 8, &lB[ldsrow * CH]);
    }
    __syncthreads();   // drains vmcnt (incl. global_load_lds) before use

    // MFMA: 16 rows x 128 cols per wave = acc[ni], ni = col block 0..7.
    f32x4 acc[8] = {};
    #pragma unroll
    for (int ks = 0; ks < 4; ks++) {
        int kg = ks * 4 + quad;                 // global k-chunk 0..15
        int chunk = (kg ^ lane15) << 3;         // swizzled LDS offset (shorts)
        bf16x8 afrag = *(const bf16x8*)&lA[(w * 16 + lane15) * CH + chunk];
        bf16x8 bfrag[8];
        #pragma unroll
        for (int ni = 0; ni < 8; ni++)
            bfrag[ni] = *(const bf16x8*)&lB[(ni * 16 + lane15) * CH + chunk];
        #pragma unroll
        for (int ni = 0; ni < 8; ni++)
            acc[ni] = __builtin_amdgcn_mfma_f32_16x16x32_bf16(
                afrag, bfrag[ni], acc[ni], 0, 0, 0);
    }

    // Epilogue. C/D layout: col = lane&15, row = quad*4 + reg.
    int labc[8];
    #pragma unroll
    for (int ni = 0; ni < 8; ni++) labc[ni] = labC[ni * 16 + lane15];

    float tc[8] = {}, pc[8] = {};    // col-side accumulators (t = total, p = pos)
    #pragma unroll
    for (int r = 0; r < 4; r++) {
        int row_l = w * 16 + quad * 4 + r;
        int lr = labR[row_l];
        float p = 0.0f, tt = 0.0f;
        #pragma unroll
        for (int ni = 0; ni < 8; ni++) {
            float e = __expf(acc[ni][r] * 10.0f);     // s / TEMP
            int col_l = ni * 16 + lane15;
            if (diag && row_l == col_l) e = 0.0f;     // remove diagonal
            float em = (labc[ni] == lr) ? e : 0.0f;
            tt += e;  p += em;
            tc[ni] += e;  pc[ni] += em;
        }
        // Butterfly over the 16 lanes holding this row's cols.
        #pragma unroll
        for (int off = 1; off < 16; off <<= 1) {
            p  += __shfl_xor(p, off);
            tt += __shfl_xor(tt, off);
        }
        if (lane15 == 0) {
            atomicAdd(&pos[b * NPTS + row0 + row_l], p);
            atomicAdd(&neg[b * NPTS + row0 + row_l], tt - p);
        }
    }

    // Col-side: reduce each lane's 4-row partial across quads (16 rows/wave),
    // stash per-wave partials in LDS, combine across the 8 waves.
    if (!diag) {
        #pragma unroll
        for (int ni = 0; ni < 8; ni++) {
            tc[ni] += __shfl_xor(tc[ni], 16);  tc[ni] += __shfl_xor(tc[ni], 32);
            pc[ni] += __shfl_xor(pc[ni], 16);  pc[ni] += __shfl_xor(pc[ni], 32);
        }
        if (quad == 0) {
            #pragma unroll
            for (int ni = 0; ni < 8; ni++) {
                colT[w][ni * 16 + lane15] = tc[ni];
                colP[w][ni * 16 + lane15] = pc[ni];
            }
        }
    }
    __syncthreads();
    if (!diag && tid < 128) {
        float T = 0.0f, P = 0.0f;
        #pragma unroll
        for (int ww = 0; ww < 8; ww++) { T += colT[ww][tid]; P += colP[ww][tid]; }
        atomicAdd(&pos[b * NPTS + col0 + tid], P);
        atomicAdd(&neg[b * NPTS + col0 + tid], T - P);
    }
}

// ---------------------------------------------------------------------------
// Kernel 3: deviation_i = log((p+n)/p); mean over all 32768 rows == mean of
// per-cloud means (equal N). Single block, 1024 threads.
// ---------------------------------------------------------------------------
__global__ __launch_bounds__(1024) void finalize_kernel(
    const float* __restrict__ pos, const float* __restrict__ neg,
    float* __restrict__ out)
{
    float acc = 0.0f;
    for (int i = threadIdx.x; i < BATCH * NPTS; i += 1024) {
        float p = pos[i];
        float t = p + neg[i];
        acc += logf(t / p);     // == -log(p / (p+n))
    }
    #pragma unroll
    for (int off = 32; off; off >>= 1) acc += __shfl_down(acc, off);
    __shared__ float red[16];
    if ((threadIdx.x & 63) == 0) red[threadIdx.x >> 6] = acc;
    __syncthreads();
    if (threadIdx.x < 16) {
        float v = red[threadIdx.x];
        #pragma unroll
        for (int off = 8; off; off >>= 1) v += __shfl_down(v, off);
        if (threadIdx.x == 0) out[0] = v * (1.0f / (BATCH * NPTS));
    }
}

extern "C" void kernel_launch(void* const* d_in, const int* in_sizes, int n_in,
                              void* d_out, int out_size, void* d_ws, size_t ws_size,
                              hipStream_t stream)
{
    const float* features = (const float*)d_in[0];
    const int*   labels   = (const int*)d_in[1];
    float*       out      = (float*)d_out;

    // Workspace layout: vn bf16 [8][4096][128] = 8 MB, then pos/neg fp32.
    __hip_bfloat16* vn = (__hip_bfloat16*)d_ws;
    float* pos = (float*)((char*)d_ws + (size_t)BATCH * NPTS * CH * sizeof(__hip_bfloat16));
    float* neg = pos + BATCH * NPTS;

    hipLaunchKernelGGL(normalize_kernel, dim3(BATCH * NPTS / 256), dim3(256), 0, stream,
                       features, vn, pos, neg);
    // 528 = 32*33/2 upper-triangular tile pairs per batch.
    hipLaunchKernelGGL(tile_kernel, dim3(528, 1, BATCH), dim3(512), 0, stream,
                       vn, labels, pos, neg);
    hipLaunchKernelGGL(finalize_kernel, dim3(1), dim3(1024), 0, stream, pos, neg, out);
}